// Round 3
// baseline (166415.820 us; speedup 1.0000x reference)
//
#include <hip/hip_runtime.h>
#include <cmath>

typedef unsigned long long u64;
typedef unsigned int u32;

#define N_SAMP 16384
#define M_C 128

// Deferred-output window: out rows [10240, 10432) hold Som + Wt until k_out2.
#define DEFER_ROW0 10240
#define DEFER_ROWS 192

// ---------------- threefry2x32, key = (0,1)  (jax.random.key(1)) ----------------
__device__ __forceinline__ void tf2x32(u32 x0, u32 x1, u32& o0, u32& o1) {
  const u32 k0 = 0u, k1 = 1u;
  const u32 ks2 = k0 ^ k1 ^ 0x1BD11BDAu;
  x0 += k0; x1 += k1;
#define RND(r) { x0 += x1; x1 = (x1 << (r)) | (x1 >> (32 - (r))); x1 ^= x0; }
  RND(13) RND(15) RND(26) RND(6)  x0 += k1;  x1 += ks2 + 1u;
  RND(17) RND(29) RND(16) RND(24) x0 += ks2; x1 += k0 + 2u;
  RND(13) RND(15) RND(26) RND(6)  x0 += k0;  x1 += k1 + 3u;
  RND(17) RND(29) RND(16) RND(24) x0 += k1;  x1 += ks2 + 4u;
  RND(13) RND(15) RND(26) RND(6)  x0 += ks2; x1 += k0 + 5u;
#undef RND
  o0 = x0; o1 = x1;
}

__global__ void k_logit(float* __restrict__ Ub, double* __restrict__ Lgb) {
  int tid = blockIdx.x * 256 + threadIdx.x;
  if (tid >= N_SAMP * M_C) return;
  u32 o0, o1; tf2x32(0u, (u32)tid, o0, o1);
  u32 bits = o0 ^ o1;
  float u = __uint_as_float((bits >> 9) | 0x3f800000u) - 1.0f;
  Ub[tid] = u;
  double lg;
  if (u <= 0.0f) lg = -1e300;         // u==0 -> threshold +inf -> s=1
  else { double ud = (double)u; lg = 0.5 * (log(ud) - log1p(-ud)); }
  Lgb[tid] = lg;
}

// ---------------- bitpack S0 rows ----------------
__global__ void k_pack(const int* __restrict__ S0, u64* __restrict__ S0m) {
  int row = blockIdx.x; int lane = threadIdx.x;
  int v0 = S0[row * 128 + lane];
  int v1 = S0[row * 128 + 64 + lane];
  u64 lo = __ballot(v0 != 0);
  u64 hi = __ballot(v1 != 0);
  if (lane == 0) { S0m[row * 2] = lo; S0m[row * 2 + 1] = hi; }
}

// column-major bit matrix: colb[c][w] bit L = S0[64w+L][c]
__global__ void k_colbits(const u64* __restrict__ S0m, u64* __restrict__ colb) {
  int wblk = blockIdx.x; int lane = threadIdx.x;
  int row = wblk * 64 + lane;
  u64 lo = S0m[row * 2], hi = S0m[row * 2 + 1];
  for (int cc = 0; cc < 64; ++cc) {
    u64 bal = __ballot((int)((lo >> cc) & 1ull));
    if (lane == 0) colb[cc * 256 + wblk] = bal;
  }
  for (int cc = 0; cc < 64; ++cc) {
    u64 bal = __ballot((int)((hi >> cc) & 1ull));
    if (lane == 0) colb[(64 + cc) * 256 + wblk] = bal;
  }
}

// StS = S0^T S0 (int), diag = St1
__global__ __launch_bounds__(256) void k_sts(const u64* __restrict__ colb, int* __restrict__ StSg) {
  int tid = blockIdx.x * 256 + threadIdx.x;
  int c = tid >> 7, k = tid & 127;
  int s = 0;
  for (int ww = 0; ww < 256; ++ww)
    s += __popcll(colb[c * 256 + ww] & colb[k * 256 + ww]);
  StSg[c * 128 + k] = s;
}

// ---------------- C = X @ W, f64 accumulation, stored f64 (np float64 reference) --------
__global__ __launch_bounds__(256) void k_gemmC(const float* __restrict__ X,
                                               const float* __restrict__ W,
                                               double* __restrict__ Cb) {
  __shared__ float Xs[16][128];
  const int t = threadIdx.x;
  const int i0 = blockIdx.x * 16;
  const int j = t & 127;
  const int ih = t >> 7;
  double acc[8];
#pragma unroll
  for (int m = 0; m < 8; ++m) acc[m] = 0.0;
  for (int k0 = 0; k0 < 1024; k0 += 128) {
    __syncthreads();
#pragma unroll
    for (int m = 0; m < 8; ++m) {
      int e = t + 256 * m;
      int r = e >> 7, cc = e & 127;
      Xs[r][cc] = X[(i0 + r) * 1024 + k0 + cc];
    }
    __syncthreads();
#pragma unroll 4
    for (int kk = 0; kk < 128; ++kk) {
      double wd = (double)W[(k0 + kk) * 128 + j];
#pragma unroll
      for (int m = 0; m < 8; ++m)
        acc[m] += (double)Xs[ih * 8 + m][kk] * wd;
    }
  }
#pragma unroll
  for (int m = 0; m < 8; ++m)
    Cb[(i0 + ih * 8 + m) * 128 + j] = acc[m];
}

// ---------------- W transpose for the output GEMM ----------------
__global__ void k_wt(const float* __restrict__ W, float* __restrict__ Wt) {
  int d0 = blockIdx.x; int j = threadIdx.x;
  Wt[j * 1024 + d0] = W[d0 * 128 + j];
}

// ---------------- decision threshold: Q = max{h : u < sigmoid_f64(2*(inp-h))} -----------
__device__ __forceinline__ bool condQ(double inpd, float uv, int hh) {
  double d = inpd - (double)hh;
  double pr = 1.0 / (1.0 + exp(-2.0 * d));
  return (double)uv < pr;
}

__device__ __forceinline__ int computeQ(double cv, float uv, double lg, int st1p) {
  double inp = 2.0 * cv - (16383.0 - 2.0 * (double)st1p) * (1.0 / 16384.0) - 0.1;
  if (uv <= 0.0f) return (1 << 20);         // u==0 -> always fires (|inhib| <= 256)
  double gd = floor(inp - lg);
  gd = fmin(fmax(gd, -300.0), 300.0);
  int h = (int)gd;
  if (condQ(inp, uv, h)) {
    if (condQ(inp, uv, h + 1)) { h++; if (condQ(inp, uv, h + 1)) h++; }
  } else {
    h--; if (!condQ(inp, uv, h)) h--;
  }
  return h;
}

// ---------------- the sequential Gibbs sweep: ONE workgroup, 1024 threads ----------------
// Per sample i:
//  * 16 waves each compute 16 R-entries; wave 1 prefetches row i+1 (double-buffered LDS);
//    waves 2-3 compute the 128 decision thresholds (f64 exp) into qbuf during the R-phase.
//  * wave0 serial phase: 4-column BLOCKS. Within a block the decision recurrence is pure
//    SALU (readlane'd scalars, sign-extended R bytes); the vector P update is one mul-add
//    fan per block. R bytes stream from LDS (1 ds_read_b32 per row-half per block,
//    prefetched 2 blocks ahead) -> no rl[16]/rh[32] register arrays -> no spill at VGPR=64.
__global__ __launch_bounds__(1024, 4) void k_gibbs(
    const double* __restrict__ Cb, const float* __restrict__ Ub,
    const double* __restrict__ Lgb, const u64* __restrict__ S0m,
    const int* __restrict__ StSg, u64* __restrict__ Som)
{
  __shared__ int RbufI[4096];      // 16KB R bytes; dword index c*32 + (d ^ (c&31))
  __shared__ __align__(16) int St1s[128];
  __shared__ int redR[8][128];
  __shared__ int redP[8][128];
  __shared__ double cbuf[2][128];
  __shared__ float ubuf[2][128];
  __shared__ double lbuf[2][128];
  __shared__ int qbuf[128];
  __shared__ u32 simask[2][4];
  __shared__ u32 pnmask[4];
  __shared__ u32 pomask[4];

  const int t = threadIdx.x;
  const int lane = t & 63;
  const int w = t >> 6;            // wave id [0,16)
  const int c = t & 127;           // R row
  const int g = t >> 7;            // k-group [0,8): columns g*16 .. g*16+15

  int sts[16];
#pragma unroll
  for (int m = 0; m < 16; ++m) sts[m] = StSg[c * 128 + g * 16 + m];

  if (t < 128) St1s[t] = StSg[t * 129];
  if (t < 4) { pnmask[t] = 0u; pomask[t] = 0u;
               simask[0][t] = (u32)(S0m[t >> 1] >> ((t & 1) * 32)); }
  if (w == 1) {    // prologue: stage sample 0's c/u/l
    cbuf[0][lane] = Cb[lane];            cbuf[0][64 + lane] = Cb[64 + lane];
    ubuf[0][lane] = Ub[lane];            ubuf[0][64 + lane] = Ub[64 + lane];
    lbuf[0][lane] = Lgb[lane];           lbuf[0][64 + lane] = Lgb[64 + lane];
  }
  __syncthreads();

#pragma unroll 1
  for (int i = 0; i < N_SAMP; ++i) {
    const int buf = i & 1;

    // ---- loader: prefetch sample i+1 into the other buffer ----
    if (w == 1 && (i + 1) < N_SAMP) {
      const int nb = buf ^ 1;
      cbuf[nb][lane]      = Cb[(i + 1) * 128 + lane];
      cbuf[nb][64 + lane] = Cb[(i + 1) * 128 + 64 + lane];
      ubuf[nb][lane]      = Ub[(i + 1) * 128 + lane];
      ubuf[nb][64 + lane] = Ub[(i + 1) * 128 + 64 + lane];
      lbuf[nb][lane]      = Lgb[(i + 1) * 128 + lane];
      lbuf[nb][64 + lane] = Lgb[(i + 1) * 128 + 64 + lane];
      if (lane < 4)
        simask[nb][lane] = (u32)(S0m[(i + 1) * 2 + (lane >> 1)] >> ((lane & 1) * 32));
    }

    // ---- q crew: waves 2,3 compute all 128 decision thresholds for sample i ----
    if (w == 2 || w == 3) {
      const int cc = t & 127;       // wave2 -> 0..63, wave3 -> 64..127
      u32 sic = (simask[buf][cc >> 5] >> (cc & 31)) & 1u;
      int st1p = St1s[cc] - (int)sic;
      qbuf[cc] = computeQ(cbuf[buf][cc], ubuf[buf][cc], lbuf[buf][cc], st1p);
    }

    // ---- R-phase: all 16 waves, 16 entries each ----
    u32 PNw = (pnmask[g >> 1] >> ((g & 1) * 16)) & 0xffffu;
    u32 POw = (pomask[g >> 1] >> ((g & 1) * 16)) & 0xffffu;
    u32 SIw = (simask[buf][g >> 1] >> ((g & 1) * 16)) & 0xffffu;
    u32 pn_c = (pnmask[c >> 5] >> (c & 31)) & 1u;
    u32 po_c = (pomask[c >> 5] >> (c & 31)) & 1u;
    u32 si_c = (simask[buf][c >> 5] >> (c & 31)) & 1u;
    u32 Pw = pn_c ? PNw : 0u;
    u32 Mw = po_c ? POw : 0u;
    u32 Sw = si_c ? SIw : 0u;
    int p1 = St1s[c] - (int)si_c;
    int cpq = 16383 - p1;
    int racc = 0, pacc = 0;
#pragma unroll
    for (int ch = 0; ch < 4; ++ch) {
      int4 q4 = *(const int4*)&St1s[g * 16 + ch * 4];
      int qarr[4] = { q4.x, q4.y, q4.z, q4.w };
      u32 word = 0u;
#pragma unroll
      for (int e = 0; e < 4; ++e) {
        const int kk = ch * 4 + e;
        int a = sts[kk] + (int)((Pw >> kk) & 1u) - (int)((Mw >> kk) & 1u);
        sts[kk] = a;
        int sik = (int)((SIw >> kk) & 1u);
        int ap = a - (int)((Sw >> kk) & 1u);
        int q = qarr[e] - sik;
        int D2 = q - ap, D3 = p1 - ap, D4 = cpq - q + ap;
        int m14 = min(ap, D4), m23 = min(D2, D3);
        bool A = m14 < m23, B = m23 < m14;
        int R = (A && (ap != D4)) ? 1 : ((B && (D2 != D3)) ? -1 : 0);
        int b24 = (int)(B && (D3 < D2)) - (int)(A && (D4 < ap));
        racc += b24;
        pacc += R * sik;
        word |= ((u32)(R & 255)) << (8 * e);
      }
      RbufI[c * 32 + ((g * 4 + ch) ^ (c & 31))] = (int)word;
    }
    redR[g][c] = racc;
    redP[g][c] = pacc;
    __syncthreads();

    if (w == 0) {
      int rlo = 0, rhi = 0, plo = 0, phi = 0;
#pragma unroll
      for (int gg = 0; gg < 8; ++gg) {
        rlo += redR[gg][lane];       rhi += redR[gg][lane + 64];
        plo += redP[gg][lane];       phi += redP[gg][lane + 64];
      }
      u64 si_lo = (u64)simask[buf][0] | ((u64)simask[buf][1] << 32);
      u64 si_hi = (u64)simask[buf][2] | ((u64)simask[buf][3] << 32);
      int qlo = qbuf[lane] - rlo;
      int qhi = qbuf[lane + 64] - rhi;
      u64 nm_lo = 0ull, nm_hi = 0ull;
      const int rowL = lane * 32;
      const int rowH = (lane + 64) * 32;
      const int sw = lane & 31;

      // ---- loop 1: columns 0..63 in 16 blocks of 4 ----
      int vL[3], vH[3];
      vL[0] = RbufI[rowL + (0 ^ sw)];  vH[0] = RbufI[rowH + (0 ^ sw)];
      vL[1] = RbufI[rowL + (1 ^ sw)];  vH[1] = RbufI[rowH + (1 ^ sw)];
#pragma unroll
      for (int b = 0; b < 16; ++b) {
        const int wl = vL[b % 3], wh = vH[b % 3];
        if (b + 2 < 16) {
          vL[(b + 2) % 3] = RbufI[rowL + ((b + 2) ^ sw)];
          vH[(b + 2) % 3] = RbufI[rowH + ((b + 2) ^ sw)];
        }
        const int j0 = 4 * b;
        // in-block R sub-matrix rows (scalar broadcast; lane j0+m of wl = row j0+m)
        int r0 = __builtin_amdgcn_readlane(wl, j0 + 0);
        int r1 = __builtin_amdgcn_readlane(wl, j0 + 1);
        int r2 = __builtin_amdgcn_readlane(wl, j0 + 2);
        int p0 = __builtin_amdgcn_readlane(plo, j0 + 0);
        int p1b = __builtin_amdgcn_readlane(plo, j0 + 1);
        int p2b = __builtin_amdgcn_readlane(plo, j0 + 2);
        int p3b = __builtin_amdgcn_readlane(plo, j0 + 3);
        int q0 = __builtin_amdgcn_readlane(qlo, j0 + 0);
        int q1 = __builtin_amdgcn_readlane(qlo, j0 + 1);
        int q2 = __builtin_amdgcn_readlane(qlo, j0 + 2);
        int q3 = __builtin_amdgcn_readlane(qlo, j0 + 3);
        int i0b = (int)((si_lo >> (j0 + 0)) & 1ull);
        int i1b = (int)((si_lo >> (j0 + 1)) & 1ull);
        int i2b = (int)((si_lo >> (j0 + 2)) & 1ull);
        int i3b = (int)((si_lo >> (j0 + 3)) & 1ull);
        // pure-SALU in-block recurrence
        int s0 = (p0 <= q0) ? 1 : 0;            int d0 = s0 - i0b;
        int pa1 = p1b + d0 * ((r0 << 16) >> 24);
        int s1 = (pa1 <= q1) ? 1 : 0;           int d1 = s1 - i1b;
        int pa2 = p2b + d0 * ((r0 << 8) >> 24) + d1 * ((r1 << 8) >> 24);
        int s2 = (pa2 <= q2) ? 1 : 0;           int d2 = s2 - i2b;
        int pa3 = p3b + d0 * (r0 >> 24) + d1 * (r1 >> 24) + d2 * (r2 >> 24);
        int s3 = (pa3 <= q3) ? 1 : 0;           int d3 = s3 - i3b;
        nm_lo |= ((u64)(u32)(s0 | (s1 << 1) | (s2 << 2) | (s3 << 3))) << j0;
        // vector P update, once per block
        plo += d0 * ((wl << 24) >> 24) + d1 * ((wl << 16) >> 24)
             + d2 * ((wl << 8) >> 24)  + d3 * (wl >> 24);
        phi += d0 * ((wh << 24) >> 24) + d1 * ((wh << 16) >> 24)
             + d2 * ((wh << 8) >> 24)  + d3 * (wh >> 24);
      }

      // ---- loop 2: columns 64..127 in 16 blocks of 4 (plo dead) ----
      int vH2[3];
      vH2[0] = RbufI[rowH + (16 ^ sw)];
      vH2[1] = RbufI[rowH + (17 ^ sw)];
#pragma unroll
      for (int b = 0; b < 16; ++b) {
        const int wv = vH2[b % 3];
        if (b + 2 < 16) vH2[(b + 2) % 3] = RbufI[rowH + ((16 + b + 2) ^ sw)];
        const int j0 = 4 * b;                 // hi-local column index
        int r0 = __builtin_amdgcn_readlane(wv, j0 + 0);
        int r1 = __builtin_amdgcn_readlane(wv, j0 + 1);
        int r2 = __builtin_amdgcn_readlane(wv, j0 + 2);
        int p0 = __builtin_amdgcn_readlane(phi, j0 + 0);
        int p1b = __builtin_amdgcn_readlane(phi, j0 + 1);
        int p2b = __builtin_amdgcn_readlane(phi, j0 + 2);
        int p3b = __builtin_amdgcn_readlane(phi, j0 + 3);
        int q0 = __builtin_amdgcn_readlane(qhi, j0 + 0);
        int q1 = __builtin_amdgcn_readlane(qhi, j0 + 1);
        int q2 = __builtin_amdgcn_readlane(qhi, j0 + 2);
        int q3 = __builtin_amdgcn_readlane(qhi, j0 + 3);
        int i0b = (int)((si_hi >> (j0 + 0)) & 1ull);
        int i1b = (int)((si_hi >> (j0 + 1)) & 1ull);
        int i2b = (int)((si_hi >> (j0 + 2)) & 1ull);
        int i3b = (int)((si_hi >> (j0 + 3)) & 1ull);
        int s0 = (p0 <= q0) ? 1 : 0;            int d0 = s0 - i0b;
        int pa1 = p1b + d0 * ((r0 << 16) >> 24);
        int s1 = (pa1 <= q1) ? 1 : 0;           int d1 = s1 - i1b;
        int pa2 = p2b + d0 * ((r0 << 8) >> 24) + d1 * ((r1 << 8) >> 24);
        int s2 = (pa2 <= q2) ? 1 : 0;           int d2 = s2 - i2b;
        int pa3 = p3b + d0 * (r0 >> 24) + d1 * (r1 >> 24) + d2 * (r2 >> 24);
        int s3 = (pa3 <= q3) ? 1 : 0;           int d3 = s3 - i3b;
        nm_hi |= ((u64)(u32)(s0 | (s1 << 1) | (s2 << 2) | (s3 << 3))) << j0;
        phi += d0 * ((wv << 24) >> 24) + d1 * ((wv << 16) >> 24)
             + d2 * ((wv << 8) >> 24)  + d3 * (wv >> 24);
      }

      St1s[lane]      += (int)((nm_lo >> lane) & 1ull) - (int)((si_lo >> lane) & 1ull);
      St1s[lane + 64] += (int)((nm_hi >> lane) & 1ull) - (int)((si_hi >> lane) & 1ull);
      if (lane == 0) {
        pnmask[0] = (u32)nm_lo; pnmask[1] = (u32)(nm_lo >> 32);
        pnmask[2] = (u32)nm_hi; pnmask[3] = (u32)(nm_hi >> 32);
        pomask[0] = (u32)si_lo; pomask[1] = (u32)(si_lo >> 32);
        pomask[2] = (u32)si_hi; pomask[3] = (u32)(si_hi >> 32);
        Som[i * 2] = nm_lo; Som[i * 2 + 1] = nm_hi;
      }
    }
    __syncthreads();
  }
}

// ---------------- out = S_new @ W^T + b, all rows EXCEPT the deferred window ----------------
__global__ __launch_bounds__(256) void k_out1(const u64* __restrict__ Som,
                                              const float* __restrict__ Wt,
                                              const float* __restrict__ bb,
                                              float* __restrict__ out) {
  if (blockIdx.x >= (DEFER_ROW0 / 4) && blockIdx.x < ((DEFER_ROW0 + DEFER_ROWS) / 4)) return;
  const int t = threadIdx.x;
  const int i0 = blockIdx.x * 4;
  u64 ml[4], mh[4];
#pragma unroll
  for (int ii = 0; ii < 4; ++ii) { ml[ii] = Som[(i0 + ii) * 2]; mh[ii] = Som[(i0 + ii) * 2 + 1]; }
  float acc[4][4];
#pragma unroll
  for (int q = 0; q < 4; ++q) {
    float bv = bb[t + 256 * q];
#pragma unroll
    for (int ii = 0; ii < 4; ++ii) acc[ii][q] = bv;
  }
#pragma unroll 2
  for (int j = 0; j < 64; ++j) {
    float wv[4];
#pragma unroll
    for (int q = 0; q < 4; ++q) wv[q] = Wt[j * 1024 + t + 256 * q];
#pragma unroll
    for (int ii = 0; ii < 4; ++ii) {
      float sb = (float)((ml[ii] >> j) & 1ull);
#pragma unroll
      for (int q = 0; q < 4; ++q) acc[ii][q] += sb * wv[q];
    }
  }
#pragma unroll 2
  for (int j = 0; j < 64; ++j) {
    float wv[4];
#pragma unroll
    for (int q = 0; q < 4; ++q) wv[q] = Wt[(64 + j) * 1024 + t + 256 * q];
#pragma unroll
    for (int ii = 0; ii < 4; ++ii) {
      float sb = (float)((mh[ii] >> j) & 1ull);
#pragma unroll
      for (int q = 0; q < 4; ++q) acc[ii][q] += sb * wv[q];
    }
  }
#pragma unroll
  for (int ii = 0; ii < 4; ++ii)
#pragma unroll
    for (int q = 0; q < 4; ++q)
      out[(i0 + ii) * 1024 + t + 256 * q] = acc[ii][q];
}

// ---------------- k_out2: ONE block writes the deferred rows last ----------------
__global__ __launch_bounds__(1024) void k_out2(const u64* __restrict__ Som,
                                               const float* __restrict__ W,
                                               const float* __restrict__ bb,
                                               float* __restrict__ out) {
  __shared__ u64 sm[DEFER_ROWS * 2];
  const int t = threadIdx.x;
  if (t < DEFER_ROWS * 2) sm[t] = Som[DEFER_ROW0 * 2 + t];
  __syncthreads();
  const float bv = bb[t];
  for (int rc = 0; rc < DEFER_ROWS / 32; ++rc) {
    float acc[32];
#pragma unroll
    for (int r = 0; r < 32; ++r) acc[r] = bv;
    for (int j = 0; j < 128; ++j) {
      float wv = W[t * 128 + j];
      const int wsel = j >> 6, sh = j & 63;
#pragma unroll
      for (int r = 0; r < 32; ++r) {
        u64 m = sm[(rc * 32 + r) * 2 + wsel];
        acc[r] += (float)((m >> sh) & 1ull) * wv;
      }
    }
#pragma unroll
    for (int r = 0; r < 32; ++r)
      out[(DEFER_ROW0 + rc * 32 + r) * 1024 + t] = acc[r];
  }
}

extern "C" void kernel_launch(void* const* d_in, const int* in_sizes, int n_in,
                              void* d_out, int out_size, void* d_ws, size_t ws_size,
                              hipStream_t stream) {
  const float* X = (const float*)d_in[0];
  const int* S0  = (const int*)d_in[1];
  const float* W = (const float*)d_in[2];
  const float* b = (const float*)d_in[3];
  float* out = (float*)d_out;

  // Scratch inside d_out (64 MB). Layout by out-row (4KB/row):
  //   rows 0..4095      : Cb  (16 MB, f64)
  //   rows 4096..8191   : Lgb (16 MB, f64)
  //   rows 8192..10239  : Ub  (8 MB, f32)
  //   rows 10240..10303 : Som (256 KB)   <- deferred window
  //   rows 10304..10431 : Wt  (512 KB)   <- deferred window
  //   rows 10432..      : S0m, colb, StSg (dead after k_gibbs)
  char* base = (char*)d_out;
  double* Cb  = (double*)(base);
  double* Lgb = (double*)(base + (16u << 20));
  float*  Ub  = (float*)(base + (32u << 20));
  u64*    Som = (u64*)(base + (40u << 20));
  float*  Wt  = (float*)(base + (40u << 20) + (256u << 10));
  u64*    S0m = (u64*)(base + (40u << 20) + (768u << 10));
  u64*    colb= (u64*)(base + (40u << 20) + (1024u << 10));
  int*    StSg= (int*)(base + (40u << 20) + (1280u << 10));

  k_pack   <<<16384, 64, 0, stream>>>(S0, S0m);
  k_colbits<<<256,   64, 0, stream>>>(S0m, colb);
  k_sts    <<<64,   256, 0, stream>>>(colb, StSg);
  k_gemmC  <<<1024, 256, 0, stream>>>(X, W, Cb);
  k_logit  <<<8192, 256, 0, stream>>>(Ub, Lgb);
  k_wt     <<<1024, 128, 0, stream>>>(W, Wt);
  k_gibbs  <<<1,   1024, 0, stream>>>(Cb, Ub, Lgb, S0m, StSg, Som);
  k_out1   <<<4096, 256, 0, stream>>>(Som, Wt, b, out);
  k_out2   <<<1,   1024, 0, stream>>>(Som, W, b, out);
}

// Round 4
// 115505.347 us; speedup vs baseline: 1.4408x; 1.4408x over previous
//
#include <hip/hip_runtime.h>
#include <cmath>

typedef unsigned long long u64;
typedef unsigned int u32;

#define N_SAMP 16384
#define M_C 128

// Deferred-output window: out rows [10240, 10432) hold Som + Wt until k_out2.
#define DEFER_ROW0 10240
#define DEFER_ROWS 192

// ---------------- threefry2x32, key = (0,1)  (jax.random.key(1)) ----------------
__device__ __forceinline__ void tf2x32(u32 x0, u32 x1, u32& o0, u32& o1) {
  const u32 k0 = 0u, k1 = 1u;
  const u32 ks2 = k0 ^ k1 ^ 0x1BD11BDAu;
  x0 += k0; x1 += k1;
#define RND(r) { x0 += x1; x1 = (x1 << (r)) | (x1 >> (32 - (r))); x1 ^= x0; }
  RND(13) RND(15) RND(26) RND(6)  x0 += k1;  x1 += ks2 + 1u;
  RND(17) RND(29) RND(16) RND(24) x0 += ks2; x1 += k0 + 2u;
  RND(13) RND(15) RND(26) RND(6)  x0 += k0;  x1 += k1 + 3u;
  RND(17) RND(29) RND(16) RND(24) x0 += k1;  x1 += ks2 + 4u;
  RND(13) RND(15) RND(26) RND(6)  x0 += ks2; x1 += k0 + 5u;
#undef RND
  o0 = x0; o1 = x1;
}

__global__ void k_logit(float* __restrict__ Ub, double* __restrict__ Lgb) {
  int tid = blockIdx.x * 256 + threadIdx.x;
  if (tid >= N_SAMP * M_C) return;
  u32 o0, o1; tf2x32(0u, (u32)tid, o0, o1);
  u32 bits = o0 ^ o1;
  float u = __uint_as_float((bits >> 9) | 0x3f800000u) - 1.0f;
  Ub[tid] = u;
  double lg;
  if (u <= 0.0f) lg = -1e300;         // u==0 -> threshold +inf -> s=1
  else { double ud = (double)u; lg = 0.5 * (log(ud) - log1p(-ud)); }
  Lgb[tid] = lg;
}

// ---------------- bitpack S0 rows ----------------
__global__ void k_pack(const int* __restrict__ S0, u64* __restrict__ S0m) {
  int row = blockIdx.x; int lane = threadIdx.x;
  int v0 = S0[row * 128 + lane];
  int v1 = S0[row * 128 + 64 + lane];
  u64 lo = __ballot(v0 != 0);
  u64 hi = __ballot(v1 != 0);
  if (lane == 0) { S0m[row * 2] = lo; S0m[row * 2 + 1] = hi; }
}

// column-major bit matrix: colb[c][w] bit L = S0[64w+L][c]
__global__ void k_colbits(const u64* __restrict__ S0m, u64* __restrict__ colb) {
  int wblk = blockIdx.x; int lane = threadIdx.x;
  int row = wblk * 64 + lane;
  u64 lo = S0m[row * 2], hi = S0m[row * 2 + 1];
  for (int cc = 0; cc < 64; ++cc) {
    u64 bal = __ballot((int)((lo >> cc) & 1ull));
    if (lane == 0) colb[cc * 256 + wblk] = bal;
  }
  for (int cc = 0; cc < 64; ++cc) {
    u64 bal = __ballot((int)((hi >> cc) & 1ull));
    if (lane == 0) colb[(64 + cc) * 256 + wblk] = bal;
  }
}

// StS = S0^T S0 (int), diag = St1
__global__ __launch_bounds__(256) void k_sts(const u64* __restrict__ colb, int* __restrict__ StSg) {
  int tid = blockIdx.x * 256 + threadIdx.x;
  int c = tid >> 7, k = tid & 127;
  int s = 0;
  for (int ww = 0; ww < 256; ++ww)
    s += __popcll(colb[c * 256 + ww] & colb[k * 256 + ww]);
  StSg[c * 128 + k] = s;
}

// ---------------- C = X @ W, f64 accumulation, stored f64 (np float64 reference) --------
__global__ __launch_bounds__(256) void k_gemmC(const float* __restrict__ X,
                                               const float* __restrict__ W,
                                               double* __restrict__ Cb) {
  __shared__ float Xs[16][128];
  const int t = threadIdx.x;
  const int i0 = blockIdx.x * 16;
  const int j = t & 127;
  const int ih = t >> 7;
  double acc[8];
#pragma unroll
  for (int m = 0; m < 8; ++m) acc[m] = 0.0;
  for (int k0 = 0; k0 < 1024; k0 += 128) {
    __syncthreads();
#pragma unroll
    for (int m = 0; m < 8; ++m) {
      int e = t + 256 * m;
      int r = e >> 7, cc = e & 127;
      Xs[r][cc] = X[(i0 + r) * 1024 + k0 + cc];
    }
    __syncthreads();
#pragma unroll 4
    for (int kk = 0; kk < 128; ++kk) {
      double wd = (double)W[(k0 + kk) * 128 + j];
#pragma unroll
      for (int m = 0; m < 8; ++m)
        acc[m] += (double)Xs[ih * 8 + m][kk] * wd;
    }
  }
#pragma unroll
  for (int m = 0; m < 8; ++m)
    Cb[(i0 + ih * 8 + m) * 128 + j] = acc[m];
}

// ---------------- W transpose for the output GEMM ----------------
__global__ void k_wt(const float* __restrict__ W, float* __restrict__ Wt) {
  int d0 = blockIdx.x; int j = threadIdx.x;
  Wt[j * 1024 + d0] = W[d0 * 128 + j];
}

// ---------------- decision threshold: Q = max{h : u < sigmoid_f64(2*(inp-h))} -----------
__device__ __forceinline__ bool condQ(double inpd, float uv, int hh) {
  double d = inpd - (double)hh;
  double pr = 1.0 / (1.0 + exp(-2.0 * d));
  return (double)uv < pr;
}

__device__ __forceinline__ int computeQ(double cv, float uv, double lg, int st1p) {
  double inp = 2.0 * cv - (16383.0 - 2.0 * (double)st1p) * (1.0 / 16384.0) - 0.1;
  if (uv <= 0.0f) return (1 << 20);         // u==0 -> always fires (|inhib| <= 256)
  double gd = floor(inp - lg);
  gd = fmin(fmax(gd, -300.0), 300.0);
  int h = (int)gd;
  if (condQ(inp, uv, h)) {
    if (condQ(inp, uv, h + 1)) { h++; if (condQ(inp, uv, h + 1)) h++; }
  } else {
    h--; if (!condQ(inp, uv, h)) h--;
  }
  return h;
}

// ---------------- the sequential Gibbs sweep: ONE workgroup, 1024 threads ----------------
// Per sample i:
//  * 16 waves each compute 16 R-entries; wave 1 prefetches row i+1 (double-buffered LDS);
//    waves 2-3 compute the 128 decision thresholds (f64 exp) into qbuf during the R-phase.
//  * wave0 serial phase: BALLOT CHAIN. p and q stay vectorized (lane j holds p_j, q_j);
//    per column j: mask = __ballot(p <= q); sn = bit j; dlt = sn - si_j (scalar);
//    p += R[:,j] * dlt (one v_mad, dlt as the single SGPR operand). Zero readlanes in
//    the chain. Row bytes stream from LDS with depth-2 rotating prefetch (static %3
//    indexing -> registers, ~25 live VGPRs, no spill).
// NOTE __launch_bounds__ 2nd arg behaves like CUDA minBlocksPerCU here: (1024,4) forced
// a 64-VGPR cap (observed VGPR_Count=64 + spill traffic). (1024,1) lifts the cap to 128.
__global__ __launch_bounds__(1024, 1) void k_gibbs(
    const double* __restrict__ Cb, const float* __restrict__ Ub,
    const double* __restrict__ Lgb, const u64* __restrict__ S0m,
    const int* __restrict__ StSg, u64* __restrict__ Som)
{
  __shared__ int RbufI[4096];      // 16KB R bytes; dword index c*32 + (d ^ (c&31))
  __shared__ __align__(16) int St1s[128];
  __shared__ int redR[8][128];
  __shared__ int redP[8][128];
  __shared__ double cbuf[2][128];
  __shared__ float ubuf[2][128];
  __shared__ double lbuf[2][128];
  __shared__ int qbuf[128];
  __shared__ u32 simask[2][4];
  __shared__ u32 pnmask[4];
  __shared__ u32 pomask[4];

  const int t = threadIdx.x;
  const int lane = t & 63;
  const int w = t >> 6;            // wave id [0,16)
  const int c = t & 127;           // R row
  const int g = t >> 7;            // k-group [0,8): columns g*16 .. g*16+15

  int sts[16];
#pragma unroll
  for (int m = 0; m < 16; ++m) sts[m] = StSg[c * 128 + g * 16 + m];

  if (t < 128) St1s[t] = StSg[t * 129];
  if (t < 4) { pnmask[t] = 0u; pomask[t] = 0u;
               simask[0][t] = (u32)(S0m[t >> 1] >> ((t & 1) * 32)); }
  if (w == 1) {    // prologue: stage sample 0's c/u/l
    cbuf[0][lane] = Cb[lane];            cbuf[0][64 + lane] = Cb[64 + lane];
    ubuf[0][lane] = Ub[lane];            ubuf[0][64 + lane] = Ub[64 + lane];
    lbuf[0][lane] = Lgb[lane];           lbuf[0][64 + lane] = Lgb[64 + lane];
  }
  __syncthreads();

#pragma unroll 1
  for (int i = 0; i < N_SAMP; ++i) {
    const int buf = i & 1;

    // ---- loader: prefetch sample i+1 into the other buffer ----
    if (w == 1 && (i + 1) < N_SAMP) {
      const int nb = buf ^ 1;
      cbuf[nb][lane]      = Cb[(i + 1) * 128 + lane];
      cbuf[nb][64 + lane] = Cb[(i + 1) * 128 + 64 + lane];
      ubuf[nb][lane]      = Ub[(i + 1) * 128 + lane];
      ubuf[nb][64 + lane] = Ub[(i + 1) * 128 + 64 + lane];
      lbuf[nb][lane]      = Lgb[(i + 1) * 128 + lane];
      lbuf[nb][64 + lane] = Lgb[(i + 1) * 128 + 64 + lane];
      if (lane < 4)
        simask[nb][lane] = (u32)(S0m[(i + 1) * 2 + (lane >> 1)] >> ((lane & 1) * 32));
    }

    // ---- q crew: waves 2,3 compute all 128 decision thresholds for sample i ----
    if (w == 2 || w == 3) {
      const int cc = t & 127;       // wave2 -> 0..63, wave3 -> 64..127
      u32 sic = (simask[buf][cc >> 5] >> (cc & 31)) & 1u;
      int st1p = St1s[cc] - (int)sic;
      qbuf[cc] = computeQ(cbuf[buf][cc], ubuf[buf][cc], lbuf[buf][cc], st1p);
    }

    // ---- R-phase: all 16 waves, 16 entries each ----
    u32 PNw = (pnmask[g >> 1] >> ((g & 1) * 16)) & 0xffffu;
    u32 POw = (pomask[g >> 1] >> ((g & 1) * 16)) & 0xffffu;
    u32 SIw = (simask[buf][g >> 1] >> ((g & 1) * 16)) & 0xffffu;
    u32 pn_c = (pnmask[c >> 5] >> (c & 31)) & 1u;
    u32 po_c = (pomask[c >> 5] >> (c & 31)) & 1u;
    u32 si_c = (simask[buf][c >> 5] >> (c & 31)) & 1u;
    u32 Pw = pn_c ? PNw : 0u;
    u32 Mw = po_c ? POw : 0u;
    u32 Sw = si_c ? SIw : 0u;
    int p1 = St1s[c] - (int)si_c;
    int cpq = 16383 - p1;
    int racc = 0, pacc = 0;
#pragma unroll
    for (int ch = 0; ch < 4; ++ch) {
      int4 q4 = *(const int4*)&St1s[g * 16 + ch * 4];
      int qarr[4] = { q4.x, q4.y, q4.z, q4.w };
      u32 word = 0u;
#pragma unroll
      for (int e = 0; e < 4; ++e) {
        const int kk = ch * 4 + e;
        int a = sts[kk] + (int)((Pw >> kk) & 1u) - (int)((Mw >> kk) & 1u);
        sts[kk] = a;
        int sik = (int)((SIw >> kk) & 1u);
        int ap = a - (int)((Sw >> kk) & 1u);
        int q = qarr[e] - sik;
        int D2 = q - ap, D3 = p1 - ap, D4 = cpq - q + ap;
        int m14 = min(ap, D4), m23 = min(D2, D3);
        bool A = m14 < m23, B = m23 < m14;
        int R = (A && (ap != D4)) ? 1 : ((B && (D2 != D3)) ? -1 : 0);
        int b24 = (int)(B && (D3 < D2)) - (int)(A && (D4 < ap));
        racc += b24;
        pacc += R * sik;
        word |= ((u32)(R & 255)) << (8 * e);
      }
      RbufI[c * 32 + ((g * 4 + ch) ^ (c & 31))] = (int)word;
    }
    redR[g][c] = racc;
    redP[g][c] = pacc;
    __syncthreads();

    if (w == 0) {
      int rlo = 0, rhi = 0, plo = 0, phi = 0;
#pragma unroll
      for (int gg = 0; gg < 8; ++gg) {
        rlo += redR[gg][lane];       rhi += redR[gg][lane + 64];
        plo += redP[gg][lane];       phi += redP[gg][lane + 64];
      }
      u64 si_lo = (u64)simask[buf][0] | ((u64)simask[buf][1] << 32);
      u64 si_hi = (u64)simask[buf][2] | ((u64)simask[buf][3] << 32);
      int qlo = qbuf[lane] - rlo;
      int qhi = qbuf[lane + 64] - rhi;
      u64 nm_lo = 0ull, nm_hi = 0ull;
      const int rowL = lane * 32;
      const int rowH = (lane + 64) * 32;
      const int sw = lane & 31;

      // ---- columns 0..63: ballot chain; stream row words, depth-2 prefetch ----
      int tl3[3], th3[3];
      tl3[0] = RbufI[rowL + (0 ^ sw)]; th3[0] = RbufI[rowH + (0 ^ sw)];
      tl3[1] = RbufI[rowL + (1 ^ sw)]; th3[1] = RbufI[rowH + (1 ^ sw)];
      // heads for the second loop, issued early (in-order LDS returns, no bubble later)
      int u2a = RbufI[rowH + (16 ^ sw)];
      int u2b = RbufI[rowH + (17 ^ sw)];
#pragma unroll
      for (int dw = 0; dw < 16; ++dw) {
        const int tl = tl3[dw % 3], th = th3[dw % 3];
        if (dw < 14) {
          tl3[(dw + 2) % 3] = RbufI[rowL + ((dw + 2) ^ sw)];
          th3[(dw + 2) % 3] = RbufI[rowH + ((dw + 2) ^ sw)];
        }
#pragma unroll
        for (int e = 0; e < 4; ++e) {
          const int j = dw * 4 + e;
          u64 mk = __ballot(plo <= qlo);
          int sn = (int)((mk >> j) & 1ull);
          int dlt = sn - (int)((si_lo >> j) & 1ull);
          nm_lo |= ((u64)(u32)sn) << j;
          int cl = (tl << (24 - 8 * e)) >> 24;
          int chh = (th << (24 - 8 * e)) >> 24;
          plo += cl * dlt;
          phi += chh * dlt;
        }
      }

      // ---- columns 64..127: phi only (plo dead) ----
      int v3[3];
      v3[0] = u2a; v3[1] = u2b;
#pragma unroll
      for (int dw = 0; dw < 16; ++dw) {
        const int th = v3[dw % 3];
        if (dw < 14)
          v3[(dw + 2) % 3] = RbufI[rowH + ((16 + dw + 2) ^ sw)];
#pragma unroll
        for (int e = 0; e < 4; ++e) {
          const int j = dw * 4 + e;              // hi-local column index
          u64 mk = __ballot(phi <= qhi);
          int sn = (int)((mk >> j) & 1ull);
          int dlt = sn - (int)((si_hi >> j) & 1ull);
          nm_hi |= ((u64)(u32)sn) << j;
          int chh = (th << (24 - 8 * e)) >> 24;
          phi += chh * dlt;
        }
      }

      St1s[lane]      += (int)((nm_lo >> lane) & 1ull) - (int)((si_lo >> lane) & 1ull);
      St1s[lane + 64] += (int)((nm_hi >> lane) & 1ull) - (int)((si_hi >> lane) & 1ull);
      if (lane == 0) {
        pnmask[0] = (u32)nm_lo; pnmask[1] = (u32)(nm_lo >> 32);
        pnmask[2] = (u32)nm_hi; pnmask[3] = (u32)(nm_hi >> 32);
        pomask[0] = (u32)si_lo; pomask[1] = (u32)(si_lo >> 32);
        pomask[2] = (u32)si_hi; pomask[3] = (u32)(si_hi >> 32);
        Som[i * 2] = nm_lo; Som[i * 2 + 1] = nm_hi;
      }
    }
    __syncthreads();
  }
}

// ---------------- out = S_new @ W^T + b, all rows EXCEPT the deferred window ----------------
__global__ __launch_bounds__(256) void k_out1(const u64* __restrict__ Som,
                                              const float* __restrict__ Wt,
                                              const float* __restrict__ bb,
                                              float* __restrict__ out) {
  if (blockIdx.x >= (DEFER_ROW0 / 4) && blockIdx.x < ((DEFER_ROW0 + DEFER_ROWS) / 4)) return;
  const int t = threadIdx.x;
  const int i0 = blockIdx.x * 4;
  u64 ml[4], mh[4];
#pragma unroll
  for (int ii = 0; ii < 4; ++ii) { ml[ii] = Som[(i0 + ii) * 2]; mh[ii] = Som[(i0 + ii) * 2 + 1]; }
  float acc[4][4];
#pragma unroll
  for (int q = 0; q < 4; ++q) {
    float bv = bb[t + 256 * q];
#pragma unroll
    for (int ii = 0; ii < 4; ++ii) acc[ii][q] = bv;
  }
#pragma unroll 2
  for (int j = 0; j < 64; ++j) {
    float wv[4];
#pragma unroll
    for (int q = 0; q < 4; ++q) wv[q] = Wt[j * 1024 + t + 256 * q];
#pragma unroll
    for (int ii = 0; ii < 4; ++ii) {
      float sb = (float)((ml[ii] >> j) & 1ull);
#pragma unroll
      for (int q = 0; q < 4; ++q) acc[ii][q] += sb * wv[q];
    }
  }
#pragma unroll 2
  for (int j = 0; j < 64; ++j) {
    float wv[4];
#pragma unroll
    for (int q = 0; q < 4; ++q) wv[q] = Wt[(64 + j) * 1024 + t + 256 * q];
#pragma unroll
    for (int ii = 0; ii < 4; ++ii) {
      float sb = (float)((mh[ii] >> j) & 1ull);
#pragma unroll
      for (int q = 0; q < 4; ++q) acc[ii][q] += sb * wv[q];
    }
  }
#pragma unroll
  for (int ii = 0; ii < 4; ++ii)
#pragma unroll
    for (int q = 0; q < 4; ++q)
      out[(i0 + ii) * 1024 + t + 256 * q] = acc[ii][q];
}

// ---------------- k_out2: ONE block writes the deferred rows last ----------------
__global__ __launch_bounds__(1024) void k_out2(const u64* __restrict__ Som,
                                               const float* __restrict__ W,
                                               const float* __restrict__ bb,
                                               float* __restrict__ out) {
  __shared__ u64 sm[DEFER_ROWS * 2];
  const int t = threadIdx.x;
  if (t < DEFER_ROWS * 2) sm[t] = Som[DEFER_ROW0 * 2 + t];
  __syncthreads();
  const float bv = bb[t];
  for (int rc = 0; rc < DEFER_ROWS / 32; ++rc) {
    float acc[32];
#pragma unroll
    for (int r = 0; r < 32; ++r) acc[r] = bv;
    for (int j = 0; j < 128; ++j) {
      float wv = W[t * 128 + j];
      const int wsel = j >> 6, sh = j & 63;
#pragma unroll
      for (int r = 0; r < 32; ++r) {
        u64 m = sm[(rc * 32 + r) * 2 + wsel];
        acc[r] += (float)((m >> sh) & 1ull) * wv;
      }
    }
#pragma unroll
    for (int r = 0; r < 32; ++r)
      out[(DEFER_ROW0 + rc * 32 + r) * 1024 + t] = acc[r];
  }
}

extern "C" void kernel_launch(void* const* d_in, const int* in_sizes, int n_in,
                              void* d_out, int out_size, void* d_ws, size_t ws_size,
                              hipStream_t stream) {
  const float* X = (const float*)d_in[0];
  const int* S0  = (const int*)d_in[1];
  const float* W = (const float*)d_in[2];
  const float* b = (const float*)d_in[3];
  float* out = (float*)d_out;

  // Scratch inside d_out (64 MB). Layout by out-row (4KB/row):
  //   rows 0..4095      : Cb  (16 MB, f64)
  //   rows 4096..8191   : Lgb (16 MB, f64)
  //   rows 8192..10239  : Ub  (8 MB, f32)
  //   rows 10240..10303 : Som (256 KB)   <- deferred window
  //   rows 10304..10431 : Wt  (512 KB)   <- deferred window
  //   rows 10432..      : S0m, colb, StSg (dead after k_gibbs)
  char* base = (char*)d_out;
  double* Cb  = (double*)(base);
  double* Lgb = (double*)(base + (16u << 20));
  float*  Ub  = (float*)(base + (32u << 20));
  u64*    Som = (u64*)(base + (40u << 20));
  float*  Wt  = (float*)(base + (40u << 20) + (256u << 10));
  u64*    S0m = (u64*)(base + (40u << 20) + (768u << 10));
  u64*    colb= (u64*)(base + (40u << 20) + (1024u << 10));
  int*    StSg= (int*)(base + (40u << 20) + (1280u << 10));

  k_pack   <<<16384, 64, 0, stream>>>(S0, S0m);
  k_colbits<<<256,   64, 0, stream>>>(S0m, colb);
  k_sts    <<<64,   256, 0, stream>>>(colb, StSg);
  k_gemmC  <<<1024, 256, 0, stream>>>(X, W, Cb);
  k_logit  <<<8192, 256, 0, stream>>>(Ub, Lgb);
  k_wt     <<<1024, 128, 0, stream>>>(W, Wt);
  k_gibbs  <<<1,   1024, 0, stream>>>(Cb, Ub, Lgb, S0m, StSg, Som);
  k_out1   <<<4096, 256, 0, stream>>>(Som, Wt, b, out);
  k_out2   <<<1,   1024, 0, stream>>>(Som, W, b, out);
}